// Round 1
// baseline (137.058 us; speedup 1.0000x reference)
//
#include <hip/hip_runtime.h>
#include <hip/hip_bf16.h>

#define IN_F   4096
#define OUT_F  4096
#define BATCH  256

typedef __attribute__((ext_vector_type(8))) short shortx8;   // 8 bf16 = 4 VGPR
typedef __attribute__((ext_vector_type(4))) float floatx4;   // MFMA C/D frag

static __device__ __forceinline__ ushort f2bf(float f) {
    union { float f; unsigned int u; } v; v.f = f;
    unsigned int u = v.u;
    unsigned int r = 0x7FFFu + ((u >> 16) & 1u);   // round-to-nearest-even
    u += r;
    return (ushort)(u >> 16);
}

static __device__ __forceinline__ float softplus_f(float x) {
    // values here are ~ -2.25; guard large x anyway
    return (x > 15.f) ? x : log1pf(__expf(x));
}

// ---------------- Kernel 1: weight sample (bf16) + KL reduction --------------
__global__ __launch_bounds__(256) void ew_kernel(
    const float* __restrict__ mu, const float* __restrict__ rho,
    const float* __restrict__ eps, const float* __restrict__ pm,
    const float* __restrict__ ps,
    ushort* __restrict__ wbf, float* __restrict__ kl_out)
{
    const int n4 = (OUT_F * IN_F) / 4;
    float kl = 0.f;
    int idx    = blockIdx.x * blockDim.x + threadIdx.x;
    int stride = gridDim.x * blockDim.x;
    for (int i = idx; i < n4; i += stride) {
        float4 m4 = ((const float4*)mu)[i];
        float4 r4 = ((const float4*)rho)[i];
        float4 e4 = ((const float4*)eps)[i];
        float4 p4 = ((const float4*)pm)[i];
        float4 s4 = ((const float4*)ps)[i];
        ushort w[4];
#pragma unroll
        for (int j = 0; j < 4; ++j) {
            float mm  = (&m4.x)[j];
            float rr  = (&r4.x)[j];
            float ee  = (&e4.x)[j];
            float pmu = (&p4.x)[j];
            float psg = (&s4.x)[j];
            float sig = softplus_f(rr);
            float wv  = fmaf(sig, ee, mm);
            w[j] = f2bf(wv);
            float dm = mm - pmu;
            kl += __logf(psg / sig) + (sig * sig + dm * dm) / (2.f * psg * psg) - 0.5f;
        }
        ushort4 packed; packed.x = w[0]; packed.y = w[1]; packed.z = w[2]; packed.w = w[3];
        ((ushort4*)wbf)[i] = packed;
    }
    // wave reduce (64 lanes) then block reduce
#pragma unroll
    for (int off = 32; off; off >>= 1) kl += __shfl_down(kl, off);
    __shared__ float wsum[4];
    if ((threadIdx.x & 63) == 0) wsum[threadIdx.x >> 6] = kl;
    __syncthreads();
    if (threadIdx.x == 0) {
        float s = wsum[0] + wsum[1] + wsum[2] + wsum[3];
        atomicAdd(kl_out, s);
    }
}

// ---------------- Kernel 2: x f32 -> bf16 -----------------------------------
__global__ __launch_bounds__(256) void xconv_kernel(
    const float* __restrict__ x, ushort* __restrict__ xb)
{
    int i = blockIdx.x * blockDim.x + threadIdx.x;   // over (BATCH*IN_F)/4
    float4 v = ((const float4*)x)[i];
    ushort4 o;
    o.x = f2bf(v.x); o.y = f2bf(v.y); o.z = f2bf(v.z); o.w = f2bf(v.w);
    ((ushort4*)xb)[i] = o;
}

// ---------------- Kernel 3: bf16 MFMA GEMM, C = A * B^T + bias --------------
// A: x_bf16 (BATCH x IN_F), B: w_bf16 (OUT_F x IN_F) both K-major.
__global__ __launch_bounds__(256) void gemm_kernel(
    const ushort* __restrict__ A, const ushort* __restrict__ B,
    const float* __restrict__ bias_mu, const float* __restrict__ bias_rho,
    const float* __restrict__ eps_b,
    float* __restrict__ C)
{
    __shared__ ushort As[64][72];   // +8 pad -> 144B row stride (16B aligned)
    __shared__ ushort Bs[64][72];

    const int tid  = threadIdx.x;
    const int m0   = blockIdx.y * 64;
    const int n0   = blockIdx.x * 64;
    const int wid  = tid >> 6;
    const int lane = tid & 63;
    const int wm   = wid >> 1;      // 0..1
    const int wn   = wid & 1;       // 0..1

    floatx4 acc[2][2] = {};

    const int r  = tid >> 2;        // staging row 0..63
    const int c0 = (tid & 3) * 16;  // staging col 0/16/32/48
    const ushort* Ag = A + (size_t)(m0 + r) * IN_F + c0;
    const ushort* Bg = B + (size_t)(n0 + r) * IN_F + c0;

    for (int k0 = 0; k0 < IN_F; k0 += 64) {
        __syncthreads();
        shortx8 a0 = *(const shortx8*)(Ag + k0);
        shortx8 a1 = *(const shortx8*)(Ag + k0 + 8);
        shortx8 b0 = *(const shortx8*)(Bg + k0);
        shortx8 b1 = *(const shortx8*)(Bg + k0 + 8);
        *(shortx8*)&As[r][c0]     = a0;
        *(shortx8*)&As[r][c0 + 8] = a1;
        *(shortx8*)&Bs[r][c0]     = b0;
        *(shortx8*)&Bs[r][c0 + 8] = b1;
        __syncthreads();
#pragma unroll
        for (int s = 0; s < 2; ++s) {
            const int kk = s * 32 + (lane >> 4) * 8;
            shortx8 af[2], bfr[2];
#pragma unroll
            for (int i = 0; i < 2; ++i)
                af[i] = *(const shortx8*)&As[wm * 32 + i * 16 + (lane & 15)][kk];
#pragma unroll
            for (int j = 0; j < 2; ++j)
                bfr[j] = *(const shortx8*)&Bs[wn * 32 + j * 16 + (lane & 15)][kk];
#pragma unroll
            for (int i = 0; i < 2; ++i)
#pragma unroll
                for (int j = 0; j < 2; ++j)
                    acc[i][j] = __builtin_amdgcn_mfma_f32_16x16x32_bf16(
                        af[i], bfr[j], acc[i][j], 0, 0, 0);
        }
    }

    // epilogue: bias sample + store.  C/D frag: col = lane&15, row = (lane>>4)*4+q
    const int cr = (lane >> 4) * 4;
    const int cc = lane & 15;
#pragma unroll
    for (int j = 0; j < 2; ++j) {
        const int nn = n0 + wn * 32 + j * 16 + cc;
        const float bv = fmaf(softplus_f(bias_rho[nn]), eps_b[nn], bias_mu[nn]);
#pragma unroll
        for (int i = 0; i < 2; ++i) {
            const int mbase = m0 + wm * 32 + i * 16 + cr;
#pragma unroll
            for (int q = 0; q < 4; ++q)
                C[(size_t)(mbase + q) * OUT_F + nn] = acc[i][j][q] + bv;
        }
    }
}

extern "C" void kernel_launch(void* const* d_in, const int* in_sizes, int n_in,
                              void* d_out, int out_size, void* d_ws, size_t ws_size,
                              hipStream_t stream) {
    const float* x        = (const float*)d_in[0];
    const float* w_mu     = (const float*)d_in[1];
    const float* w_rho    = (const float*)d_in[2];
    const float* b_mu     = (const float*)d_in[3];
    const float* b_rho    = (const float*)d_in[4];
    const float* eps_w    = (const float*)d_in[5];
    const float* eps_b    = (const float*)d_in[6];
    const float* prior_mu = (const float*)d_in[7];
    const float* prior_sg = (const float*)d_in[8];

    float* out = (float*)d_out;
    const size_t KL_IDX = (size_t)BATCH * OUT_F;

    ushort* w_bf = (ushort*)d_ws;                                   // 32 MB
    ushort* x_bf = (ushort*)((char*)d_ws + (size_t)OUT_F * IN_F * 2); // 2 MB

    // zero the KL accumulator slot
    hipMemsetAsync((char*)d_out + KL_IDX * sizeof(float), 0, sizeof(float), stream);

    // weight sample + KL
    ew_kernel<<<2048, 256, 0, stream>>>(w_mu, w_rho, eps_w, prior_mu, prior_sg,
                                        w_bf, out + KL_IDX);
    // x -> bf16
    xconv_kernel<<<(BATCH * IN_F / 4) / 256, 256, 0, stream>>>(x, x_bf);

    // GEMM + bias
    dim3 grid(OUT_F / 64, BATCH / 64);
    gemm_kernel<<<grid, 256, 0, stream>>>(x_bf, w_bf, b_mu, b_rho, eps_b, out);
}

// Round 2
// 123.677 us; speedup vs baseline: 1.1082x; 1.1082x over previous
//
#include <hip/hip_runtime.h>
#include <hip/hip_bf16.h>

#define IN_F   4096
#define OUT_F  4096
#define BATCH  256

#define EW_BLOCKS 2048
#define EW_THREADS 256
#define EW_ITERS  8   // EW_BLOCKS*EW_THREADS*4*EW_ITERS == OUT_F*IN_F

typedef __attribute__((ext_vector_type(8))) short shortx8;   // 8 bf16 = 4 VGPR
typedef __attribute__((ext_vector_type(4))) float floatx4;   // MFMA C/D frag

static __device__ __forceinline__ ushort f2bf(float f) {
    union { float f; unsigned int u; } v; v.f = f;
    unsigned int u = v.u;
    unsigned int r = 0x7FFFu + ((u >> 16) & 1u);   // round-to-nearest-even
    u += r;
    return (ushort)(u >> 16);
}

// fast softplus: log(1+e^x); rho ~ -2.25 so no overflow concerns, but guard anyway
static __device__ __forceinline__ float softplus_fast(float x) {
    return (x > 15.f) ? x : __logf(1.f + __expf(x));
}

// ---------------- Kernel 1: weight sample (bf16) + KL partial sums -----------
__global__ __launch_bounds__(256) void ew_kernel(
    const float* __restrict__ mu, const float* __restrict__ rho,
    const float* __restrict__ eps, const float* __restrict__ pm,
    const float* __restrict__ ps,
    ushort* __restrict__ wbf, float* __restrict__ partials)
{
    const int tid = blockIdx.x * EW_THREADS + threadIdx.x;   // float4 index base
    float kl = 0.f;
#pragma unroll 2
    for (int it = 0; it < EW_ITERS; ++it) {
        const int i = tid + it * (EW_BLOCKS * EW_THREADS);
        float4 m4 = ((const float4*)mu)[i];
        float4 r4 = ((const float4*)rho)[i];
        float4 e4 = ((const float4*)eps)[i];
        float4 p4 = ((const float4*)pm)[i];
        float4 s4 = ((const float4*)ps)[i];
        ushort w[4];
#pragma unroll
        for (int j = 0; j < 4; ++j) {
            float mm  = (&m4.x)[j];
            float rr  = (&r4.x)[j];
            float ee  = (&e4.x)[j];
            float pmu = (&p4.x)[j];
            float psg = (&s4.x)[j];
            float sig = softplus_fast(rr);
            w[j] = f2bf(fmaf(sig, ee, mm));
            float dm   = mm - pmu;
            float inv2 = 0.5f * __builtin_amdgcn_rcpf(psg * psg);
            // log(psg/sig) = log(psg) - log(sig); no division anywhere
            kl += (__logf(psg) - __logf(sig)) - 0.5f
                + fmaf(sig, sig, dm * dm) * inv2;
        }
        ushort4 packed; packed.x = w[0]; packed.y = w[1]; packed.z = w[2]; packed.w = w[3];
        ((ushort4*)wbf)[i] = packed;
    }
    // wave reduce (64 lanes) then block reduce -> one partial per block
#pragma unroll
    for (int off = 32; off; off >>= 1) kl += __shfl_down(kl, off);
    __shared__ float wsum[4];
    if ((threadIdx.x & 63) == 0) wsum[threadIdx.x >> 6] = kl;
    __syncthreads();
    if (threadIdx.x == 0)
        partials[blockIdx.x] = wsum[0] + wsum[1] + wsum[2] + wsum[3];
}

// ---------------- Kernel 1b: final KL reduction (deterministic) --------------
__global__ __launch_bounds__(256) void kl_reduce_kernel(
    const float* __restrict__ partials, float* __restrict__ kl_out)
{
    float s = 0.f;
#pragma unroll
    for (int it = 0; it < EW_BLOCKS / 256; ++it)
        s += partials[threadIdx.x + it * 256];
#pragma unroll
    for (int off = 32; off; off >>= 1) s += __shfl_down(s, off);
    __shared__ float wsum[4];
    if ((threadIdx.x & 63) == 0) wsum[threadIdx.x >> 6] = s;
    __syncthreads();
    if (threadIdx.x == 0)
        *kl_out = wsum[0] + wsum[1] + wsum[2] + wsum[3];
}

// ---------------- Kernel 2: x f32 -> bf16 -----------------------------------
__global__ __launch_bounds__(256) void xconv_kernel(
    const float* __restrict__ x, ushort* __restrict__ xb)
{
    int i = blockIdx.x * blockDim.x + threadIdx.x;   // over (BATCH*IN_F)/4
    float4 v = ((const float4*)x)[i];
    ushort4 o;
    o.x = f2bf(v.x); o.y = f2bf(v.y); o.z = f2bf(v.z); o.w = f2bf(v.w);
    ((ushort4*)xb)[i] = o;
}

// ---------------- Kernel 3: bf16 MFMA GEMM, C = A * B^T + bias --------------
// A: x_bf16 (BATCH x IN_F), B: w_bf16 (OUT_F x IN_F) both K-major.
__global__ __launch_bounds__(256) void gemm_kernel(
    const ushort* __restrict__ A, const ushort* __restrict__ B,
    const float* __restrict__ bias_mu, const float* __restrict__ bias_rho,
    const float* __restrict__ eps_b,
    float* __restrict__ C)
{
    __shared__ ushort As[64][72];   // +8 pad -> 144B row stride (16B aligned)
    __shared__ ushort Bs[64][72];

    const int tid  = threadIdx.x;
    const int m0   = blockIdx.y * 64;
    const int n0   = blockIdx.x * 64;
    const int wid  = tid >> 6;
    const int lane = tid & 63;
    const int wm   = wid >> 1;      // 0..1
    const int wn   = wid & 1;       // 0..1

    floatx4 acc[2][2] = {};

    const int r  = tid >> 2;        // staging row 0..63
    const int c0 = (tid & 3) * 16;  // staging col 0/16/32/48
    const ushort* Ag = A + (size_t)(m0 + r) * IN_F + c0;
    const ushort* Bg = B + (size_t)(n0 + r) * IN_F + c0;

    for (int k0 = 0; k0 < IN_F; k0 += 64) {
        __syncthreads();
        shortx8 a0 = *(const shortx8*)(Ag + k0);
        shortx8 a1 = *(const shortx8*)(Ag + k0 + 8);
        shortx8 b0 = *(const shortx8*)(Bg + k0);
        shortx8 b1 = *(const shortx8*)(Bg + k0 + 8);
        *(shortx8*)&As[r][c0]     = a0;
        *(shortx8*)&As[r][c0 + 8] = a1;
        *(shortx8*)&Bs[r][c0]     = b0;
        *(shortx8*)&Bs[r][c0 + 8] = b1;
        __syncthreads();
#pragma unroll
        for (int s = 0; s < 2; ++s) {
            const int kk = s * 32 + (lane >> 4) * 8;
            shortx8 af[2], bfr[2];
#pragma unroll
            for (int i = 0; i < 2; ++i)
                af[i] = *(const shortx8*)&As[wm * 32 + i * 16 + (lane & 15)][kk];
#pragma unroll
            for (int j = 0; j < 2; ++j)
                bfr[j] = *(const shortx8*)&Bs[wn * 32 + j * 16 + (lane & 15)][kk];
#pragma unroll
            for (int i = 0; i < 2; ++i)
#pragma unroll
                for (int j = 0; j < 2; ++j)
                    acc[i][j] = __builtin_amdgcn_mfma_f32_16x16x32_bf16(
                        af[i], bfr[j], acc[i][j], 0, 0, 0);
        }
    }

    // epilogue: bias sample + store.  C/D frag: col = lane&15, row = (lane>>4)*4+q
    const int cr = (lane >> 4) * 4;
    const int cc = lane & 15;
#pragma unroll
    for (int j = 0; j < 2; ++j) {
        const int nn = n0 + wn * 32 + j * 16 + cc;
        const float bv = fmaf(softplus_fast(bias_rho[nn]), eps_b[nn], bias_mu[nn]);
#pragma unroll
        for (int i = 0; i < 2; ++i) {
            const int mbase = m0 + wm * 32 + i * 16 + cr;
#pragma unroll
            for (int q = 0; q < 4; ++q)
                C[(size_t)(mbase + q) * OUT_F + nn] = acc[i][j][q] + bv;
        }
    }
}

extern "C" void kernel_launch(void* const* d_in, const int* in_sizes, int n_in,
                              void* d_out, int out_size, void* d_ws, size_t ws_size,
                              hipStream_t stream) {
    const float* x        = (const float*)d_in[0];
    const float* w_mu     = (const float*)d_in[1];
    const float* w_rho    = (const float*)d_in[2];
    const float* b_mu     = (const float*)d_in[3];
    const float* b_rho    = (const float*)d_in[4];
    const float* eps_w    = (const float*)d_in[5];
    const float* eps_b    = (const float*)d_in[6];
    const float* prior_mu = (const float*)d_in[7];
    const float* prior_sg = (const float*)d_in[8];

    float* out = (float*)d_out;
    const size_t KL_IDX = (size_t)BATCH * OUT_F;

    ushort* w_bf     = (ushort*)d_ws;                                     // 32 MB
    ushort* x_bf     = (ushort*)((char*)d_ws + (size_t)OUT_F * IN_F * 2); // 2 MB
    float*  partials = (float*)((char*)d_ws + (size_t)OUT_F * IN_F * 2
                                            + (size_t)BATCH * IN_F * 2);  // 8 KB

    // weight sample + KL partials
    ew_kernel<<<EW_BLOCKS, EW_THREADS, 0, stream>>>(
        w_mu, w_rho, eps_w, prior_mu, prior_sg, w_bf, partials);
    // x -> bf16
    xconv_kernel<<<(BATCH * IN_F / 4) / 256, 256, 0, stream>>>(x, x_bf);
    // final KL value (deterministic single-block reduce)
    kl_reduce_kernel<<<1, 256, 0, stream>>>(partials, out + KL_IDX);
    // GEMM + bias
    dim3 grid(OUT_F / 64, BATCH / 64);
    gemm_kernel<<<grid, 256, 0, stream>>>(x_bf, w_bf, b_mu, b_rho, eps_b, out);
}